// Round 5
// baseline (1967.220 us; speedup 1.0000x reference)
//
#include <hip/hip_runtime.h>

#define NPTS 2048
#define BATCH 8
#define KNN 20

// ---------------------------------------------------------------------------
// sq[i] = sum_c fin[i, c]^2 over row-major fin (i = b*2048+n), ascending fmaf.
__global__ void k_sqnorm(const float* __restrict__ fin, int stride, int off,
                         float* __restrict__ sq, int C) {
  int i = blockIdx.x * 256 + threadIdx.x;   // over B*N
  const float* r = fin + (size_t)i * stride + off;
  float a = 0.f;
  for (int c = 0; c < C; ++c) a = fmaf(r[c], r[c], a);
  sq[i] = a;
}

// ---------------------------------------------------------------------------
// Screen GEMM for one batch: D[n,m] = 2*dot(x_n,x_m) - sq[n] - sq[m]
// 64x64 tile, BK=16 (zero-padded past KK), 4x4 microtile. D is 2048x2048.
__global__ void __launch_bounds__(256) k_screen(const float* __restrict__ fin,
                                                int stride, int off, int KK,
                                                const float* __restrict__ sq,
                                                int b, float* __restrict__ D) {
  __shared__ float As[16][68];
  __shared__ float Bs[16][68];
  int tid = threadIdx.x;
  int n0 = blockIdx.y * 64, m0 = blockIdx.x * 64;
  const float* fb = fin + (size_t)b * NPTS * stride + off;
  int lr = tid >> 2;            // 0..63
  int lk = (tid & 3) * 4;       // 0,4,8,12
  float acc[4][4];
  #pragma unroll
  for (int i = 0; i < 4; ++i)
    #pragma unroll
    for (int j = 0; j < 4; ++j) acc[i][j] = 0.f;
  for (int k0 = 0; k0 < KK; k0 += 16) {
    float4 av, bv;
    const float* arow = fb + (size_t)(n0 + lr) * stride + k0 + lk;
    const float* brow = fb + (size_t)(m0 + lr) * stride + k0 + lk;
    int rem = KK - k0;
    if (lk + 4 <= rem) { av = *(const float4*)arow; bv = *(const float4*)brow; }
    else {
      av.x = (lk + 0 < rem) ? arow[0] : 0.f;  bv.x = (lk + 0 < rem) ? brow[0] : 0.f;
      av.y = (lk + 1 < rem) ? arow[1] : 0.f;  bv.y = (lk + 1 < rem) ? brow[1] : 0.f;
      av.z = (lk + 2 < rem) ? arow[2] : 0.f;  bv.z = (lk + 2 < rem) ? brow[2] : 0.f;
      av.w = (lk + 3 < rem) ? arow[3] : 0.f;  bv.w = (lk + 3 < rem) ? brow[3] : 0.f;
    }
    __syncthreads();
    As[lk+0][lr] = av.x; As[lk+1][lr] = av.y; As[lk+2][lr] = av.z; As[lk+3][lr] = av.w;
    Bs[lk+0][lr] = bv.x; Bs[lk+1][lr] = bv.y; Bs[lk+2][lr] = bv.z; Bs[lk+3][lr] = bv.w;
    __syncthreads();
    int ty = tid >> 4, tx = tid & 15;
    #pragma unroll
    for (int kk = 0; kk < 16; ++kk) {
      float4 a = *(const float4*)&As[kk][ty * 4];
      float4 b2 = *(const float4*)&Bs[kk][tx * 4];
      acc[0][0] = fmaf(a.x, b2.x, acc[0][0]); acc[0][1] = fmaf(a.x, b2.y, acc[0][1]);
      acc[0][2] = fmaf(a.x, b2.z, acc[0][2]); acc[0][3] = fmaf(a.x, b2.w, acc[0][3]);
      acc[1][0] = fmaf(a.y, b2.x, acc[1][0]); acc[1][1] = fmaf(a.y, b2.y, acc[1][1]);
      acc[1][2] = fmaf(a.y, b2.z, acc[1][2]); acc[1][3] = fmaf(a.y, b2.w, acc[1][3]);
      acc[2][0] = fmaf(a.z, b2.x, acc[2][0]); acc[2][1] = fmaf(a.z, b2.y, acc[2][1]);
      acc[2][2] = fmaf(a.z, b2.z, acc[2][2]); acc[2][3] = fmaf(a.z, b2.w, acc[2][3]);
      acc[3][0] = fmaf(a.w, b2.x, acc[3][0]); acc[3][1] = fmaf(a.w, b2.y, acc[3][1]);
      acc[3][2] = fmaf(a.w, b2.z, acc[3][2]); acc[3][3] = fmaf(a.w, b2.w, acc[3][3]);
    }
  }
  int ty = tid >> 4, tx = tid & 15;
  const float* sqb = sq + b * NPTS;
  #pragma unroll
  for (int i = 0; i < 4; ++i) {
    float sn = sqb[n0 + ty * 4 + i];
    #pragma unroll
    for (int j = 0; j < 4; ++j) {
      float sm = sqb[m0 + tx * 4 + j];
      D[(size_t)(n0 + ty * 4 + i) * NPTS + m0 + tx * 4 + j] = 2.f * acc[i][j] - sn - sm;
    }
  }
}

// ---------------------------------------------------------------------------
// Order-preserving float->uint map (monotone increasing).
__device__ inline unsigned f2u(float f) {
  unsigned b = __float_as_uint(f);
  return b ^ (unsigned)(((int)b >> 31) | 0x80000000);
}

// Per-row selection: 3-level radix threshold for the top-32 screened values,
// compact candidates (>= 24-bit threshold prefix, cap 64), exact fp64 rescore
// from row-major fin, rank-by-count -> top-20 (dist asc, index asc).
// All LDS regions are wave-private; only wave-level fences needed.
__device__ inline void row_select(const float (&dv)[32], int wt,
                                  unsigned* __restrict__ hist,   // [256]
                                  unsigned* __restrict__ cntp,   // [1]
                                  int*      __restrict__ candc,  // [64]
                                  double*   __restrict__ candd,  // [64]
                                  const float* __restrict__ ctrrow,
                                  const float* __restrict__ finb, // + b*2048*stride
                                  int stride, int off, int C,
                                  int* __restrict__ outp) {
  unsigned u[32];
  #pragma unroll
  for (int s = 0; s < 32; ++s) u[s] = f2u(dv[s]);

  unsigned K = 32;        // rank target within current prefix class
  unsigned pbits = 0;     // selected prefix bits (positioned)
  unsigned maskhi = 0;    // mask of refined bits
  for (int lvl = 0; lvl < 3; ++lvl) {
    int sh = 24 - 8 * lvl;
    #pragma unroll
    for (int j = 0; j < 4; ++j) hist[wt * 4 + j] = 0u;
    __threadfence_block();
    #pragma unroll
    for (int s = 0; s < 32; ++s) {
      unsigned uu = u[s];
      if ((uu & maskhi) == pbits) atomicAdd(&hist[(uu >> sh) & 255u], 1u);
    }
    __threadfence_block();
    unsigned h[4];
    #pragma unroll
    for (int j = 0; j < 4; ++j) h[j] = hist[wt * 4 + j];
    unsigned lsum = h[0] + h[1] + h[2] + h[3];
    unsigned acc = lsum;
    #pragma unroll
    for (int o = 1; o < 64; o <<= 1) {       // inclusive suffix sum over lanes
      unsigned t = __shfl_down(acc, o, 64);
      acc += (wt + o < 64) ? t : 0u;
    }
    unsigned S = acc - lsum;                 // sum over strictly-higher lanes
    unsigned ca3 = S;
    unsigned ca2 = ca3 + h[3];
    unsigned ca1 = ca2 + h[2];
    unsigned ca0 = ca1 + h[1];
    unsigned ca[4] = {ca0, ca1, ca2, ca3};
    int myb = -1; unsigned myK = 0;
    #pragma unroll
    for (int j = 3; j >= 0; --j)
      if (myb < 0 && ca[j] < K && K <= ca[j] + h[j]) { myb = 4 * wt + j; myK = K - ca[j]; }
    unsigned long long mk = __ballot(myb >= 0);
    int src = __ffsll((unsigned long long)mk) - 1;
    int B = __shfl(myb, src, 64);
    K = (unsigned)__shfl((int)myK, src, 64);
    pbits |= ((unsigned)B & 255u) << sh;
    maskhi |= 255u << sh;
  }
  unsigned T = pbits;                        // low byte zero: superset threshold

  if (wt == 0) *cntp = 0u;
  __threadfence_block();
  #pragma unroll
  for (int s = 0; s < 32; ++s) {
    if (u[s] >= T) {
      unsigned pos = atomicAdd(cntp, 1u);
      if (pos < 64u) candc[pos] = ((s >> 2) << 8) + (wt << 2) + (s & 3);
    }
  }
  __threadfence_block();
  int cnt = (int)min(*cntp, 64u);            // >=32 by construction

  // exact fp64 rescore (sequential ascending-c fma)
  int m; double dd;
  if (wt < cnt) {
    m = candc[wt];
    dd = 0.0;
    const float* nr = finb + (size_t)m * stride + off;
    int C4 = C & ~3;
    for (int c = 0; c < C4; c += 4) {
      float4 xv = *(const float4*)(nr + c);
      double d0 = (double)ctrrow[c + 0] - (double)xv.x;
      dd = fma(d0, d0, dd);
      double d1 = (double)ctrrow[c + 1] - (double)xv.y;
      dd = fma(d1, d1, dd);
      double d2 = (double)ctrrow[c + 2] - (double)xv.z;
      dd = fma(d2, d2, dd);
      double d3 = (double)ctrrow[c + 3] - (double)xv.w;
      dd = fma(d3, d3, dd);
    }
    for (int c = C4; c < C; ++c) {
      double df = (double)ctrrow[c] - (double)nr[c];
      dd = fma(df, df, dd);
    }
  } else { dd = 1e300; m = 1 << 30; }
  candd[wt] = dd;
  __threadfence_block();

  // rank = #{j: (dd_j, m_j) < (dd, m)}; ranks distinct (m unique per cand)
  int rank = 0;
  for (int j = 0; j < cnt; ++j) {
    double dj = candd[j]; int mj = candc[j];
    rank += (dj < dd || (dj == dd && mj < m)) ? 1 : 0;
  }
  if (wt < cnt && rank < KNN) outp[rank] = m;
}

// One wave per row, 4 rows per block. Reads the materialized D row.
__global__ void __launch_bounds__(256) k_select(const float* __restrict__ D,
                                                const float* __restrict__ fin,
                                                int stride, int off, int C, int b,
                                                int* __restrict__ idxo) {
  __shared__ unsigned histS[4][256];
  __shared__ unsigned cntS[4];
  __shared__ int candcS[4][64];
  __shared__ double canddS[4][64];
  int tid = threadIdx.x;
  int wave = tid >> 6, wt = tid & 63;
  int n = blockIdx.x * 4 + wave;
  float dv[32];
  const float4* rp = (const float4*)(D + (size_t)n * NPTS) + wt;
  #pragma unroll
  for (int j = 0; j < 8; ++j) {
    float4 v = rp[64 * j];
    dv[j*4+0] = v.x; dv[j*4+1] = v.y; dv[j*4+2] = v.z; dv[j*4+3] = v.w;
  }
  const float* finb = fin + (size_t)b * NPTS * stride;
  row_select(dv, wt, histS[wave], &cntS[wave], candcS[wave], canddS[wave],
             finb + (size_t)n * stride + off, finb, stride, off, C,
             idxo + ((size_t)b * NPTS + n) * KNN);
}

// ---------------------------------------------------------------------------
// Edge-conv via Z/T decomposition:
//   y[n,k,f] = w1[f]·x_{m(n,k)} + (w2−w1)[f]·x_n = Z[m,f] + T[n,f]

// WC prep: rows 0..F-1 = w1 = w[f][0:C]; rows F..2F-1 = w[f][C:2C]-w[f][0:C]
__global__ void k_wprep(const float* __restrict__ w, float* __restrict__ wc,
                        int C, int F) {
  int i = blockIdx.x * 256 + threadIdx.x;
  if (i >= 2 * F * C) return;
  int n = i / C, c = i - n * C;
  wc[i] = (n < F) ? w[(size_t)n * 2 * C + c]
                  : w[(size_t)(n - F) * 2 * C + C + c] - w[(size_t)(n - F) * 2 * C + c];
}

// ZT(16384 x W2F) = A(16384 x C; row stride lda, col offset off) @ WC^T
template <int C>
__global__ void __launch_bounds__(256) k_zgemm(const float* __restrict__ A, int lda, int off,
                                               const float* __restrict__ WC, int W2F,
                                               float* __restrict__ ZT) {
  __shared__ float As[C][68];
  __shared__ float Ws[C][68];
  int tid = threadIdx.x;
  int m0 = blockIdx.y * 64, f0 = blockIdx.x * 64;
  for (int i = tid; i < 64 * C; i += 256) {
    int r = i / C, c = i - r * C;
    As[c][r] = A[(size_t)(m0 + r) * lda + off + c];
    Ws[c][r] = WC[(size_t)(f0 + r) * C + c];
  }
  __syncthreads();
  int ty = tid >> 4, tx = tid & 15;
  float acc[4][4];
  #pragma unroll
  for (int i = 0; i < 4; ++i)
    #pragma unroll
    for (int j = 0; j < 4; ++j) acc[i][j] = 0.f;
  for (int kk = 0; kk < C; ++kk) {
    float4 a = *(const float4*)&As[kk][ty * 4];
    float4 b = *(const float4*)&Ws[kk][tx * 4];
    acc[0][0] = fmaf(a.x, b.x, acc[0][0]); acc[0][1] = fmaf(a.x, b.y, acc[0][1]);
    acc[0][2] = fmaf(a.x, b.z, acc[0][2]); acc[0][3] = fmaf(a.x, b.w, acc[0][3]);
    acc[1][0] = fmaf(a.y, b.x, acc[1][0]); acc[1][1] = fmaf(a.y, b.y, acc[1][1]);
    acc[1][2] = fmaf(a.y, b.z, acc[1][2]); acc[1][3] = fmaf(a.y, b.w, acc[1][3]);
    acc[2][0] = fmaf(a.z, b.x, acc[2][0]); acc[2][1] = fmaf(a.z, b.y, acc[2][1]);
    acc[2][2] = fmaf(a.z, b.z, acc[2][2]); acc[2][3] = fmaf(a.z, b.w, acc[2][3]);
    acc[3][0] = fmaf(a.w, b.x, acc[3][0]); acc[3][1] = fmaf(a.w, b.y, acc[3][1]);
    acc[3][2] = fmaf(a.w, b.z, acc[3][2]); acc[3][3] = fmaf(a.w, b.w, acc[3][3]);
  }
  #pragma unroll
  for (int i = 0; i < 4; ++i)
    #pragma unroll
    for (int j = 0; j < 4; ++j)
      ZT[(size_t)(m0 + ty * 4 + i) * W2F + f0 + tx * 4 + j] = acc[i][j];
}

// Gather-reduce: per (n,f) max/min over k of Z[m_k,f]+T[n,f], select by
// sign(g[f]) (BN+leaky monotone), write pre-BN into CAT, fp64 stats.
template <int F, int PL, int SP>
__global__ void __launch_bounds__(256) k_gather(const float* __restrict__ ZT, int W2F,
                                                const int* __restrict__ idxb,
                                                const float* __restrict__ g,
                                                float* __restrict__ cat, int catoff,
                                                double* __restrict__ stats) {
  int tid = threadIdx.x;
  int pl = tid / F, f = tid & (F - 1);
  float gg = g[f];
  double s = 0.0, ss = 0.0;
  int nbase = blockIdx.x * (PL * SP) + pl * SP;
  for (int sp = 0; sp < SP; ++sp) {
    int n = nbase + sp;
    int gbase = n & ~(NPTS - 1);
    const int* ip = idxb + n * KNN;
    float T = ZT[(size_t)n * W2F + F + f];
    float mx = -1e30f, mn = 1e30f;
    #pragma unroll
    for (int k = 0; k < KNN; ++k) {
      int m = ip[k];
      float z = ZT[(size_t)(gbase + m) * W2F + f];
      float y = z + T;
      mx = fmaxf(mx, y); mn = fminf(mn, y);
      double yd = (double)y;
      s += yd; ss = fma(yd, yd, ss);
    }
    cat[(size_t)n * 512 + catoff + f] = (gg >= 0.f) ? mx : mn;
  }
  atomicAdd(&stats[f], s);
  atomicAdd(&stats[F + f], ss);
}

// BN + leaky, in place on the CAT slice.
__global__ void k_bn(float* __restrict__ cat, const double* __restrict__ stats,
                     const float* __restrict__ g, const float* __restrict__ bb,
                     int Fbits, int catoff) {
  int i = blockIdx.x * 256 + threadIdx.x;   // over B*N*F, f fastest
  int F = 1 << Fbits;
  int f = i & (F - 1);
  int bn = i >> Fbits;
  const double invCnt = 1.0 / (double)(BATCH * NPTS * KNN);
  double mean = stats[f] * invCnt;
  double ex2  = stats[F + f] * invCnt;
  double var  = ex2 - mean * mean;
  if (var < 0.0) var = 0.0;
  double rs   = rsqrt(var + 1e-5);
  float* p = &cat[(size_t)bn * 512 + catoff + f];
  float y = *p;
  float t = (float)((double)g[f] * ((double)y - mean) * rs + (double)bb[f]);
  *p = (t >= 0.f) ? t : 0.2f * t;
}

// ---------------------------------------------------------------------------
// Final GEMM: CAT(16384x512) @ wf^T(512x1024) -> out(16384x1024).
__global__ void __launch_bounds__(256) k_gemm(const float* __restrict__ A,
                                              const float* __restrict__ Bw,
                                              float* __restrict__ Cc) {
  __shared__ float As[16][68];
  __shared__ float Bs[16][68];
  int tid = threadIdx.x;
  int m0 = blockIdx.y * 64, f0 = blockIdx.x * 64;
  int ty = tid >> 4, tx = tid & 15;
  int lr = tid >> 2;            // 0..63
  int lk = (tid & 3) * 4;       // 0,4,8,12
  float acc[4][4];
  #pragma unroll
  for (int i = 0; i < 4; ++i)
    #pragma unroll
    for (int j = 0; j < 4; ++j) acc[i][j] = 0.f;
  for (int k0 = 0; k0 < 512; k0 += 16) {
    float4 av = *(const float4*)&A [(size_t)(m0 + lr) * 512 + k0 + lk];
    float4 bv = *(const float4*)&Bw[(size_t)(f0 + lr) * 512 + k0 + lk];
    __syncthreads();
    As[lk+0][lr] = av.x; As[lk+1][lr] = av.y; As[lk+2][lr] = av.z; As[lk+3][lr] = av.w;
    Bs[lk+0][lr] = bv.x; Bs[lk+1][lr] = bv.y; Bs[lk+2][lr] = bv.z; Bs[lk+3][lr] = bv.w;
    __syncthreads();
    #pragma unroll
    for (int kk = 0; kk < 16; ++kk) {
      float4 a = *(const float4*)&As[kk][ty * 4];
      float4 b = *(const float4*)&Bs[kk][tx * 4];
      acc[0][0] = fmaf(a.x, b.x, acc[0][0]); acc[0][1] = fmaf(a.x, b.y, acc[0][1]);
      acc[0][2] = fmaf(a.x, b.z, acc[0][2]); acc[0][3] = fmaf(a.x, b.w, acc[0][3]);
      acc[1][0] = fmaf(a.y, b.x, acc[1][0]); acc[1][1] = fmaf(a.y, b.y, acc[1][1]);
      acc[1][2] = fmaf(a.y, b.z, acc[1][2]); acc[1][3] = fmaf(a.y, b.w, acc[1][3]);
      acc[2][0] = fmaf(a.z, b.x, acc[2][0]); acc[2][1] = fmaf(a.z, b.y, acc[2][1]);
      acc[2][2] = fmaf(a.z, b.z, acc[2][2]); acc[2][3] = fmaf(a.z, b.w, acc[2][3]);
      acc[3][0] = fmaf(a.w, b.x, acc[3][0]); acc[3][1] = fmaf(a.w, b.y, acc[3][1]);
      acc[3][2] = fmaf(a.w, b.z, acc[3][2]); acc[3][3] = fmaf(a.w, b.w, acc[3][3]);
    }
  }
  #pragma unroll
  for (int i = 0; i < 4; ++i)
    #pragma unroll
    for (int j = 0; j < 4; ++j)
      Cc[(size_t)(m0 + ty * 4 + i) * 1024 + f0 + tx * 4 + j] = acc[i][j];
}

// Per-channel sum/sumsq (fp64) over 16384 rows of out(16384x1024).
__global__ void k_fstats(const float* __restrict__ y, double* __restrict__ st) {
  int tid = threadIdx.x;
  int r0 = blockIdx.x * 256;
  double s[4] = {0,0,0,0}, ss[4] = {0,0,0,0};
  for (int r = r0; r < r0 + 256; ++r) {
    const float* row = y + (size_t)r * 1024;
    #pragma unroll
    for (int q = 0; q < 4; ++q) {
      double v = (double)row[tid + 256 * q];
      s[q] += v; ss[q] = fma(v, v, ss[q]);
    }
  }
  #pragma unroll
  for (int q = 0; q < 4; ++q) {
    atomicAdd(&st[tid + 256 * q], s[q]);
    atomicAdd(&st[1024 + tid + 256 * q], ss[q]);
  }
}

__global__ void k_fnorm(float* __restrict__ y, const double* __restrict__ st,
                        const float* __restrict__ g, const float* __restrict__ bb) {
  int i = blockIdx.x * 256 + threadIdx.x;
  int f = i & 1023;
  const double invCnt = 1.0 / 16384.0;
  double mean = st[f] * invCnt;
  double ex2  = st[1024 + f] * invCnt;
  double var  = ex2 - mean * mean;
  if (var < 0.0) var = 0.0;
  double rs   = rsqrt(var + 1e-5);
  float v = y[i];
  float t = (float)((double)g[f] * ((double)v - mean) * rs + (double)bb[f]);
  y[i] = (t >= 0.f) ? t : 0.2f * t;
}

// ---------------------------------------------------------------------------
extern "C" void kernel_launch(void* const* d_in, const int* in_sizes, int n_in,
                              void* d_out, int out_size, void* d_ws, size_t ws_size,
                              hipStream_t stream) {
  const float* x  = (const float*)d_in[0];
  const float* W[4]  = {(const float*)d_in[1], (const float*)d_in[4],
                        (const float*)d_in[7], (const float*)d_in[10]};
  const float* G[4]  = {(const float*)d_in[2], (const float*)d_in[5],
                        (const float*)d_in[8], (const float*)d_in[11]};
  const float* Bb[4] = {(const float*)d_in[3], (const float*)d_in[6],
                        (const float*)d_in[9], (const float*)d_in[12]};
  const float* wf = (const float*)d_in[13];
  const float* gf = (const float*)d_in[14];
  const float* bf = (const float*)d_in[15];
  float* out = (float*)d_out;

  // workspace carve: ~70 MB. ZT region doubles as the per-batch D scratch
  // (D = 2048*2048 = 4,194,304 f <= ZT 8,388,608 f); all knn-path launches
  // for a layer complete before zgemm overwrites ZT (stream-ordered).
  float* ws  = (float*)d_ws;
  float* SQ  = ws;                 // 16384 f
  float* CAT = SQ + 16384;         // 16384*512 = 8,388,608 f
  float* ZT  = CAT + 8388608;      // 8,388,608 f (also D scratch)
  float* WC  = ZT + 8388608;       // 65,536 f
  double* ST = (double*)(WC + 65536);      // 2048 doubles
  int*   IDX = (int*)(ST + 2048);  // 16384*20 ints

  const int Cs[4]      = {3, 64, 64, 128};
  const int Fs[4]      = {64, 64, 128, 256};
  const int Fbits[4]   = {6, 6, 7, 8};
  const int offs[4]    = {0, 0, 64, 128};
  const int strides[4] = {3, 512, 512, 512};
  const int catoffs[4] = {0, 64, 128, 256};

  for (int l = 0; l < 4; ++l) {
    const float* fin = (l == 0) ? x : CAT;
    int C = Cs[l], F = Fs[l];
    int W2F = 2 * F;
    k_sqnorm<<<dim3(BATCH * NPTS / 256), 256, 0, stream>>>(fin, strides[l], offs[l], SQ, C);
    for (int b = 0; b < BATCH; ++b) {
      k_screen<<<dim3(NPTS / 64, NPTS / 64), 256, 0, stream>>>(fin, strides[l], offs[l], C, SQ, b, ZT);
      k_select<<<dim3(NPTS / 4), 256, 0, stream>>>(ZT, fin, strides[l], offs[l], C, b, IDX);
    }
    k_wprep<<<dim3((2 * F * C + 255) / 256), 256, 0, stream>>>(W[l], WC, C, F);
    switch (C) {
      case 3:   k_zgemm<3>  <<<dim3(W2F / 64, 256), 256, 0, stream>>>(fin, strides[l], offs[l], WC, W2F, ZT); break;
      case 64:  k_zgemm<64> <<<dim3(W2F / 64, 256), 256, 0, stream>>>(fin, strides[l], offs[l], WC, W2F, ZT); break;
      default:  k_zgemm<128><<<dim3(W2F / 64, 256), 256, 0, stream>>>(fin, strides[l], offs[l], WC, W2F, ZT); break;
    }
    (void)hipMemsetAsync(ST, 0, 2 * F * sizeof(double), stream);
    switch (F) {
      case 64:  k_gather<64, 4, 16><<<dim3(16384 / 64), 256, 0, stream>>>(ZT, W2F, IDX, G[l], CAT, catoffs[l], ST); break;
      case 128: k_gather<128, 2, 16><<<dim3(16384 / 32), 256, 0, stream>>>(ZT, W2F, IDX, G[l], CAT, catoffs[l], ST); break;
      default:  k_gather<256, 1, 16><<<dim3(16384 / 16), 256, 0, stream>>>(ZT, W2F, IDX, G[l], CAT, catoffs[l], ST); break;
    }
    k_bn<<<dim3(BATCH * NPTS * F / 256), 256, 0, stream>>>(CAT, ST, G[l], Bb[l], Fbits[l], catoffs[l]);
  }

  k_gemm<<<dim3(1024 / 64, 16384 / 64), 256, 0, stream>>>(CAT, wf, out);
  (void)hipMemsetAsync(ST, 0, 2048 * sizeof(double), stream);
  k_fstats<<<dim3(64), 256, 0, stream>>>(out, ST);
  k_fnorm<<<dim3(16384 * 1024 / 256), 256, 0, stream>>>(out, ST, gf, bf);
}

// Round 6
// 1679.601 us; speedup vs baseline: 1.1712x; 1.1712x over previous
//
#include <hip/hip_runtime.h>

#define NPTS 2048
#define BATCH 8
#define KNN 20

// ---------------------------------------------------------------------------
// sq[i] = sum_c fin[i, c]^2 over row-major fin (i = b*2048+n), ascending fmaf.
__global__ void k_sqnorm(const float* __restrict__ fin, int stride, int off,
                         float* __restrict__ sq, int C) {
  int i = blockIdx.x * 256 + threadIdx.x;   // over B*N
  const float* r = fin + (size_t)i * stride + off;
  float a = 0.f;
  for (int c = 0; c < C; ++c) a = fmaf(r[c], r[c], a);
  sq[i] = a;
}

// ---------------------------------------------------------------------------
// Screen GEMM, 2 batches per dispatch (blockIdx.z selects batch + D half):
// D[n,m] = 2*dot(x_n,x_m) - sq[n] - sq[m];  64x64 tile, BK=16 zero-padded.
__global__ void __launch_bounds__(256) k_screen(const float* __restrict__ fin,
                                                int stride, int off, int KK,
                                                const float* __restrict__ sq,
                                                int bbase, float* __restrict__ Dbase) {
  __shared__ float As[16][68];
  __shared__ float Bs[16][68];
  int tid = threadIdx.x;
  int b = bbase + blockIdx.z;
  float* D = Dbase + (size_t)blockIdx.z * NPTS * NPTS;
  int n0 = blockIdx.y * 64, m0 = blockIdx.x * 64;
  const float* fb = fin + (size_t)b * NPTS * stride + off;
  int lr = tid >> 2;            // 0..63
  int lk = (tid & 3) * 4;       // 0,4,8,12
  float acc[4][4];
  #pragma unroll
  for (int i = 0; i < 4; ++i)
    #pragma unroll
    for (int j = 0; j < 4; ++j) acc[i][j] = 0.f;
  for (int k0 = 0; k0 < KK; k0 += 16) {
    float4 av, bv;
    const float* arow = fb + (size_t)(n0 + lr) * stride + k0 + lk;
    const float* brow = fb + (size_t)(m0 + lr) * stride + k0 + lk;
    int rem = KK - k0;
    if (lk + 4 <= rem) { av = *(const float4*)arow; bv = *(const float4*)brow; }
    else {
      av.x = (lk + 0 < rem) ? arow[0] : 0.f;  bv.x = (lk + 0 < rem) ? brow[0] : 0.f;
      av.y = (lk + 1 < rem) ? arow[1] : 0.f;  bv.y = (lk + 1 < rem) ? brow[1] : 0.f;
      av.z = (lk + 2 < rem) ? arow[2] : 0.f;  bv.z = (lk + 2 < rem) ? brow[2] : 0.f;
      av.w = (lk + 3 < rem) ? arow[3] : 0.f;  bv.w = (lk + 3 < rem) ? brow[3] : 0.f;
    }
    __syncthreads();
    As[lk+0][lr] = av.x; As[lk+1][lr] = av.y; As[lk+2][lr] = av.z; As[lk+3][lr] = av.w;
    Bs[lk+0][lr] = bv.x; Bs[lk+1][lr] = bv.y; Bs[lk+2][lr] = bv.z; Bs[lk+3][lr] = bv.w;
    __syncthreads();
    int ty = tid >> 4, tx = tid & 15;
    #pragma unroll
    for (int kk = 0; kk < 16; ++kk) {
      float4 a = *(const float4*)&As[kk][ty * 4];
      float4 b2 = *(const float4*)&Bs[kk][tx * 4];
      acc[0][0] = fmaf(a.x, b2.x, acc[0][0]); acc[0][1] = fmaf(a.x, b2.y, acc[0][1]);
      acc[0][2] = fmaf(a.x, b2.z, acc[0][2]); acc[0][3] = fmaf(a.x, b2.w, acc[0][3]);
      acc[1][0] = fmaf(a.y, b2.x, acc[1][0]); acc[1][1] = fmaf(a.y, b2.y, acc[1][1]);
      acc[1][2] = fmaf(a.y, b2.z, acc[1][2]); acc[1][3] = fmaf(a.y, b2.w, acc[1][3]);
      acc[2][0] = fmaf(a.z, b2.x, acc[2][0]); acc[2][1] = fmaf(a.z, b2.y, acc[2][1]);
      acc[2][2] = fmaf(a.z, b2.z, acc[2][2]); acc[2][3] = fmaf(a.z, b2.w, acc[2][3]);
      acc[3][0] = fmaf(a.w, b2.x, acc[3][0]); acc[3][1] = fmaf(a.w, b2.y, acc[3][1]);
      acc[3][2] = fmaf(a.w, b2.z, acc[3][2]); acc[3][3] = fmaf(a.w, b2.w, acc[3][3]);
    }
  }
  int ty = tid >> 4, tx = tid & 15;
  const float* sqb = sq + b * NPTS;
  #pragma unroll
  for (int i = 0; i < 4; ++i) {
    float sn = sqb[n0 + ty * 4 + i];
    #pragma unroll
    for (int j = 0; j < 4; ++j) {
      float sm = sqb[m0 + tx * 4 + j];
      D[(size_t)(n0 + ty * 4 + i) * NPTS + m0 + tx * 4 + j] = 2.f * acc[i][j] - sn - sm;
    }
  }
}

// ---------------------------------------------------------------------------
// Order-preserving float->uint map (monotone increasing).
__device__ inline unsigned f2u(float f) {
  unsigned b = __float_as_uint(f);
  return b ^ (unsigned)(((int)b >> 31) | 0x80000000);
}

// Per-row selection, conflict-free:
//  1) bisection threshold T = largest 256-multiple P with count(u>=P) >= 32
//     (provably identical to the 3-level radix prefix floor)
//  2) ballot compaction of {u>=T} in deterministic s-major order, cap 128
//  3) exact fp64 rescore (ascending-c fma) of <=2 candidates/lane
//  4) rank-by-count over (dd, m) -> top-20 output
__device__ inline void row_select(const float (&dv)[32], int wt,
                                  int*    __restrict__ candc,   // [128] LDS
                                  double* __restrict__ candd,   // [128] LDS
                                  const float* __restrict__ ctrrow,
                                  const float* __restrict__ finb,
                                  int stride, int off, int C,
                                  int* __restrict__ outp) {
  unsigned u[32];
  #pragma unroll
  for (int s = 0; s < 32; ++s) u[s] = f2u(dv[s]);

  unsigned P = 0u;
  for (int k = 31; k >= 8; --k) {
    unsigned Pt = P | (1u << k);
    int bc = 0;
    #pragma unroll
    for (int s = 0; s < 32; ++s) bc += (u[s] >= Pt) ? 1 : 0;
    #pragma unroll
    for (int o = 1; o < 64; o <<= 1) bc += __shfl_xor(bc, o, 64);
    if (bc >= 32) P = Pt;
  }
  const unsigned T = P;

  int cnt = 0;
  #pragma unroll
  for (int s = 0; s < 32; ++s) {
    bool pred = (u[s] >= T);
    unsigned long long mk = __ballot(pred);
    if (pred) {
      int pos = cnt + (int)__popcll(mk & ((1ull << wt) - 1ull));
      if (pos < 128) candc[pos] = ((s >> 2) << 8) + (wt << 2) + (s & 3);
    }
    cnt += (int)__popcll(mk);
  }
  if (cnt > 128) cnt = 128;
  __threadfence_block();

  double dq[2]; int mq[2];
  #pragma unroll
  for (int q = 0; q < 2; ++q) {
    int ci = wt + 64 * q;
    if (ci < cnt) {
      int m = candc[ci];
      double dd = 0.0;
      const float* nr = finb + (size_t)m * stride + off;
      int C4 = C & ~3;
      for (int c = 0; c < C4; c += 4) {
        float4 xv = *(const float4*)(nr + c);
        double d0 = (double)ctrrow[c + 0] - (double)xv.x; dd = fma(d0, d0, dd);
        double d1 = (double)ctrrow[c + 1] - (double)xv.y; dd = fma(d1, d1, dd);
        double d2 = (double)ctrrow[c + 2] - (double)xv.z; dd = fma(d2, d2, dd);
        double d3 = (double)ctrrow[c + 3] - (double)xv.w; dd = fma(d3, d3, dd);
      }
      for (int c = C4; c < C; ++c) {
        double df = (double)ctrrow[c] - (double)nr[c]; dd = fma(df, df, dd);
      }
      dq[q] = dd; mq[q] = m;
    } else { dq[q] = 1e300; mq[q] = 1 << 30; }
    candd[ci] = dq[q];
  }
  __threadfence_block();

  int r0 = 0, r1 = 0;
  for (int j = 0; j < cnt; ++j) {
    double dj = candd[j]; int mj = candc[j];
    r0 += (dj < dq[0] || (dj == dq[0] && mj < mq[0])) ? 1 : 0;
    r1 += (dj < dq[1] || (dj == dq[1] && mj < mq[1])) ? 1 : 0;
  }
  if (wt < cnt && r0 < KNN) outp[r0] = mq[0];
  if (wt + 64 < cnt && r1 < KNN) outp[r1] = mq[1];
}

// One wave per row, 4 rows per block, 2 batches per dispatch (blockIdx.y).
__global__ void __launch_bounds__(256) k_select(const float* __restrict__ Dbase,
                                                const float* __restrict__ fin,
                                                int stride, int off, int C, int bbase,
                                                int* __restrict__ idxo) {
  __shared__ int candcS[4][128];
  __shared__ double canddS[4][128];
  int tid = threadIdx.x;
  int wave = tid >> 6, wt = tid & 63;
  int b = bbase + blockIdx.y;
  const float* D = Dbase + (size_t)blockIdx.y * NPTS * NPTS;
  int n = blockIdx.x * 4 + wave;
  float dv[32];
  const float4* rp = (const float4*)(D + (size_t)n * NPTS) + wt;
  #pragma unroll
  for (int j = 0; j < 8; ++j) {
    float4 v = rp[64 * j];
    dv[j*4+0] = v.x; dv[j*4+1] = v.y; dv[j*4+2] = v.z; dv[j*4+3] = v.w;
  }
  const float* finb = fin + (size_t)b * NPTS * stride;
  row_select(dv, wt, candcS[wave], canddS[wave],
             finb + (size_t)n * stride + off, finb, stride, off, C,
             idxo + ((size_t)b * NPTS + n) * KNN);
}

// ---------------------------------------------------------------------------
// Edge-conv via Z/T decomposition:
//   y[n,k,f] = w1[f]·x_{m(n,k)} + (w2−w1)[f]·x_n = Z[m,f] + T[n,f]

// WC prep: rows 0..F-1 = w1 = w[f][0:C]; rows F..2F-1 = w[f][C:2C]-w[f][0:C]
__global__ void k_wprep(const float* __restrict__ w, float* __restrict__ wc,
                        int C, int F) {
  int i = blockIdx.x * 256 + threadIdx.x;
  if (i >= 2 * F * C) return;
  int n = i / C, c = i - n * C;
  wc[i] = (n < F) ? w[(size_t)n * 2 * C + c]
                  : w[(size_t)(n - F) * 2 * C + C + c] - w[(size_t)(n - F) * 2 * C + c];
}

// ZT(16384 x W2F) = A(16384 x C; row stride lda, col offset off) @ WC^T
template <int C>
__global__ void __launch_bounds__(256) k_zgemm(const float* __restrict__ A, int lda, int off,
                                               const float* __restrict__ WC, int W2F,
                                               float* __restrict__ ZT) {
  __shared__ float As[C][68];
  __shared__ float Ws[C][68];
  int tid = threadIdx.x;
  int m0 = blockIdx.y * 64, f0 = blockIdx.x * 64;
  for (int i = tid; i < 64 * C; i += 256) {
    int r = i / C, c = i - r * C;
    As[c][r] = A[(size_t)(m0 + r) * lda + off + c];
    Ws[c][r] = WC[(size_t)(f0 + r) * C + c];
  }
  __syncthreads();
  int ty = tid >> 4, tx = tid & 15;
  float acc[4][4];
  #pragma unroll
  for (int i = 0; i < 4; ++i)
    #pragma unroll
    for (int j = 0; j < 4; ++j) acc[i][j] = 0.f;
  for (int kk = 0; kk < C; ++kk) {
    float4 a = *(const float4*)&As[kk][ty * 4];
    float4 b = *(const float4*)&Ws[kk][tx * 4];
    acc[0][0] = fmaf(a.x, b.x, acc[0][0]); acc[0][1] = fmaf(a.x, b.y, acc[0][1]);
    acc[0][2] = fmaf(a.x, b.z, acc[0][2]); acc[0][3] = fmaf(a.x, b.w, acc[0][3]);
    acc[1][0] = fmaf(a.y, b.x, acc[1][0]); acc[1][1] = fmaf(a.y, b.y, acc[1][1]);
    acc[1][2] = fmaf(a.y, b.z, acc[1][2]); acc[1][3] = fmaf(a.y, b.w, acc[1][3]);
    acc[2][0] = fmaf(a.z, b.x, acc[2][0]); acc[2][1] = fmaf(a.z, b.y, acc[2][1]);
    acc[2][2] = fmaf(a.z, b.z, acc[2][2]); acc[2][3] = fmaf(a.z, b.w, acc[2][3]);
    acc[3][0] = fmaf(a.w, b.x, acc[3][0]); acc[3][1] = fmaf(a.w, b.y, acc[3][1]);
    acc[3][2] = fmaf(a.w, b.z, acc[3][2]); acc[3][3] = fmaf(a.w, b.w, acc[3][3]);
  }
  #pragma unroll
  for (int i = 0; i < 4; ++i)
    #pragma unroll
    for (int j = 0; j < 4; ++j)
      ZT[(size_t)(m0 + ty * 4 + i) * W2F + f0 + tx * 4 + j] = acc[i][j];
}

// Gather-reduce: per (n,f) max/min over k of Z[m_k,f]+T[n,f], select by
// sign(g[f]) (BN+leaky monotone), write pre-BN into CAT, fp64 stats.
template <int F, int PL, int SP>
__global__ void __launch_bounds__(256) k_gather(const float* __restrict__ ZT, int W2F,
                                                const int* __restrict__ idxb,
                                                const float* __restrict__ g,
                                                float* __restrict__ cat, int catoff,
                                                double* __restrict__ stats) {
  int tid = threadIdx.x;
  int pl = tid / F, f = tid & (F - 1);
  float gg = g[f];
  double s = 0.0, ss = 0.0;
  int nbase = blockIdx.x * (PL * SP) + pl * SP;
  for (int sp = 0; sp < SP; ++sp) {
    int n = nbase + sp;
    int gbase = n & ~(NPTS - 1);
    const int* ip = idxb + n * KNN;
    float T = ZT[(size_t)n * W2F + F + f];
    float mx = -1e30f, mn = 1e30f;
    #pragma unroll
    for (int k = 0; k < KNN; ++k) {
      int m = ip[k];
      float z = ZT[(size_t)(gbase + m) * W2F + f];
      float y = z + T;
      mx = fmaxf(mx, y); mn = fminf(mn, y);
      double yd = (double)y;
      s += yd; ss = fma(yd, yd, ss);
    }
    cat[(size_t)n * 512 + catoff + f] = (gg >= 0.f) ? mx : mn;
  }
  atomicAdd(&stats[f], s);
  atomicAdd(&stats[F + f], ss);
}

// BN + leaky, in place on the CAT slice.
__global__ void k_bn(float* __restrict__ cat, const double* __restrict__ stats,
                     const float* __restrict__ g, const float* __restrict__ bb,
                     int Fbits, int catoff) {
  int i = blockIdx.x * 256 + threadIdx.x;   // over B*N*F, f fastest
  int F = 1 << Fbits;
  int f = i & (F - 1);
  int bn = i >> Fbits;
  const double invCnt = 1.0 / (double)(BATCH * NPTS * KNN);
  double mean = stats[f] * invCnt;
  double ex2  = stats[F + f] * invCnt;
  double var  = ex2 - mean * mean;
  if (var < 0.0) var = 0.0;
  double rs   = rsqrt(var + 1e-5);
  float* p = &cat[(size_t)bn * 512 + catoff + f];
  float y = *p;
  float t = (float)((double)g[f] * ((double)y - mean) * rs + (double)bb[f]);
  *p = (t >= 0.f) ? t : 0.2f * t;
}

// ---------------------------------------------------------------------------
// Final GEMM: CAT(16384x512) @ wf^T(512x1024) -> out(16384x1024).
__global__ void __launch_bounds__(256) k_gemm(const float* __restrict__ A,
                                              const float* __restrict__ Bw,
                                              float* __restrict__ Cc) {
  __shared__ float As[16][68];
  __shared__ float Bs[16][68];
  int tid = threadIdx.x;
  int m0 = blockIdx.y * 64, f0 = blockIdx.x * 64;
  int ty = tid >> 4, tx = tid & 15;
  int lr = tid >> 2;            // 0..63
  int lk = (tid & 3) * 4;       // 0,4,8,12
  float acc[4][4];
  #pragma unroll
  for (int i = 0; i < 4; ++i)
    #pragma unroll
    for (int j = 0; j < 4; ++j) acc[i][j] = 0.f;
  for (int k0 = 0; k0 < 512; k0 += 16) {
    float4 av = *(const float4*)&A [(size_t)(m0 + lr) * 512 + k0 + lk];
    float4 bv = *(const float4*)&Bw[(size_t)(f0 + lr) * 512 + k0 + lk];
    __syncthreads();
    As[lk+0][lr] = av.x; As[lk+1][lr] = av.y; As[lk+2][lr] = av.z; As[lk+3][lr] = av.w;
    Bs[lk+0][lr] = bv.x; Bs[lk+1][lr] = bv.y; Bs[lk+2][lr] = bv.z; Bs[lk+3][lr] = bv.w;
    __syncthreads();
    #pragma unroll
    for (int kk = 0; kk < 16; ++kk) {
      float4 a = *(const float4*)&As[kk][ty * 4];
      float4 b = *(const float4*)&Bs[kk][tx * 4];
      acc[0][0] = fmaf(a.x, b.x, acc[0][0]); acc[0][1] = fmaf(a.x, b.y, acc[0][1]);
      acc[0][2] = fmaf(a.x, b.z, acc[0][2]); acc[0][3] = fmaf(a.x, b.w, acc[0][3]);
      acc[1][0] = fmaf(a.y, b.x, acc[1][0]); acc[1][1] = fmaf(a.y, b.y, acc[1][1]);
      acc[1][2] = fmaf(a.y, b.z, acc[1][2]); acc[1][3] = fmaf(a.y, b.w, acc[1][3]);
      acc[2][0] = fmaf(a.z, b.x, acc[2][0]); acc[2][1] = fmaf(a.z, b.y, acc[2][1]);
      acc[2][2] = fmaf(a.z, b.z, acc[2][2]); acc[2][3] = fmaf(a.z, b.w, acc[2][3]);
      acc[3][0] = fmaf(a.w, b.x, acc[3][0]); acc[3][1] = fmaf(a.w, b.y, acc[3][1]);
      acc[3][2] = fmaf(a.w, b.z, acc[3][2]); acc[3][3] = fmaf(a.w, b.w, acc[3][3]);
    }
  }
  #pragma unroll
  for (int i = 0; i < 4; ++i)
    #pragma unroll
    for (int j = 0; j < 4; ++j)
      Cc[(size_t)(m0 + ty * 4 + i) * 1024 + f0 + tx * 4 + j] = acc[i][j];
}

// Per-channel sum/sumsq (fp64) over 16384 rows of out(16384x1024).
__global__ void k_fstats(const float* __restrict__ y, double* __restrict__ st) {
  int tid = threadIdx.x;
  int r0 = blockIdx.x * 256;
  double s[4] = {0,0,0,0}, ss[4] = {0,0,0,0};
  for (int r = r0; r < r0 + 256; ++r) {
    const float* row = y + (size_t)r * 1024;
    #pragma unroll
    for (int q = 0; q < 4; ++q) {
      double v = (double)row[tid + 256 * q];
      s[q] += v; ss[q] = fma(v, v, ss[q]);
    }
  }
  #pragma unroll
  for (int q = 0; q < 4; ++q) {
    atomicAdd(&st[tid + 256 * q], s[q]);
    atomicAdd(&st[1024 + tid + 256 * q], ss[q]);
  }
}

__global__ void k_fnorm(float* __restrict__ y, const double* __restrict__ st,
                        const float* __restrict__ g, const float* __restrict__ bb) {
  int i = blockIdx.x * 256 + threadIdx.x;
  int f = i & 1023;
  const double invCnt = 1.0 / 16384.0;
  double mean = st[f] * invCnt;
  double ex2  = st[1024 + f] * invCnt;
  double var  = ex2 - mean * mean;
  if (var < 0.0) var = 0.0;
  double rs   = rsqrt(var + 1e-5);
  float v = y[i];
  float t = (float)((double)g[f] * ((double)v - mean) * rs + (double)bb[f]);
  y[i] = (t >= 0.f) ? t : 0.2f * t;
}

// ---------------------------------------------------------------------------
extern "C" void kernel_launch(void* const* d_in, const int* in_sizes, int n_in,
                              void* d_out, int out_size, void* d_ws, size_t ws_size,
                              hipStream_t stream) {
  const float* x  = (const float*)d_in[0];
  const float* W[4]  = {(const float*)d_in[1], (const float*)d_in[4],
                        (const float*)d_in[7], (const float*)d_in[10]};
  const float* G[4]  = {(const float*)d_in[2], (const float*)d_in[5],
                        (const float*)d_in[8], (const float*)d_in[11]};
  const float* Bb[4] = {(const float*)d_in[3], (const float*)d_in[6],
                        (const float*)d_in[9], (const float*)d_in[12]};
  const float* wf = (const float*)d_in[13];
  const float* gf = (const float*)d_in[14];
  const float* bf = (const float*)d_in[15];
  float* out = (float*)d_out;

  // workspace carve: ~70 MB. ZT region doubles as the 2-batch D scratch
  // (2*2048*2048 = 8,388,608 f == ZT size); knn launches for a batch pair
  // complete before the next pair / zgemm overwrite it (stream-ordered).
  float* ws  = (float*)d_ws;
  float* SQ  = ws;                 // 16384 f
  float* CAT = SQ + 16384;         // 16384*512 = 8,388,608 f
  float* ZT  = CAT + 8388608;      // 8,388,608 f (also D scratch, 2 batches)
  float* WC  = ZT + 8388608;       // 65,536 f
  double* ST = (double*)(WC + 65536);      // 2048 doubles
  int*   IDX = (int*)(ST + 2048);  // 16384*20 ints

  const int Cs[4]      = {3, 64, 64, 128};
  const int Fs[4]      = {64, 64, 128, 256};
  const int Fbits[4]   = {6, 6, 7, 8};
  const int offs[4]    = {0, 0, 64, 128};
  const int strides[4] = {3, 512, 512, 512};
  const int catoffs[4] = {0, 64, 128, 256};

  for (int l = 0; l < 4; ++l) {
    const float* fin = (l == 0) ? x : CAT;
    int C = Cs[l], F = Fs[l];
    int W2F = 2 * F;
    k_sqnorm<<<dim3(BATCH * NPTS / 256), 256, 0, stream>>>(fin, strides[l], offs[l], SQ, C);
    for (int bb = 0; bb < BATCH; bb += 2) {
      k_screen<<<dim3(NPTS / 64, NPTS / 64, 2), 256, 0, stream>>>(fin, strides[l], offs[l], C, SQ, bb, ZT);
      k_select<<<dim3(NPTS / 4, 2), 256, 0, stream>>>(ZT, fin, strides[l], offs[l], C, bb, IDX);
    }
    k_wprep<<<dim3((2 * F * C + 255) / 256), 256, 0, stream>>>(W[l], WC, C, F);
    switch (C) {
      case 3:   k_zgemm<3>  <<<dim3(W2F / 64, 256), 256, 0, stream>>>(fin, strides[l], offs[l], WC, W2F, ZT); break;
      case 64:  k_zgemm<64> <<<dim3(W2F / 64, 256), 256, 0, stream>>>(fin, strides[l], offs[l], WC, W2F, ZT); break;
      default:  k_zgemm<128><<<dim3(W2F / 64, 256), 256, 0, stream>>>(fin, strides[l], offs[l], WC, W2F, ZT); break;
    }
    (void)hipMemsetAsync(ST, 0, 2 * F * sizeof(double), stream);
    switch (F) {
      case 64:  k_gather<64, 4, 16><<<dim3(16384 / 64), 256, 0, stream>>>(ZT, W2F, IDX, G[l], CAT, catoffs[l], ST); break;
      case 128: k_gather<128, 2, 16><<<dim3(16384 / 32), 256, 0, stream>>>(ZT, W2F, IDX, G[l], CAT, catoffs[l], ST); break;
      default:  k_gather<256, 1, 16><<<dim3(16384 / 16), 256, 0, stream>>>(ZT, W2F, IDX, G[l], CAT, catoffs[l], ST); break;
    }
    k_bn<<<dim3(BATCH * NPTS * F / 256), 256, 0, stream>>>(CAT, ST, G[l], Bb[l], Fbits[l], catoffs[l]);
  }

  k_gemm<<<dim3(1024 / 64, 16384 / 64), 256, 0, stream>>>(CAT, wf, out);
  (void)hipMemsetAsync(ST, 0, 2048 * sizeof(double), stream);
  k_fstats<<<dim3(64), 256, 0, stream>>>(out, ST);
  k_fnorm<<<dim3(16384 * 1024 / 256), 256, 0, stream>>>(out, ST, gf, bf);
}